// Round 1
// baseline (334.892 us; speedup 1.0000x reference)
//
#include <hip/hip_runtime.h>
#include <math.h>

// BRC loss: per-sample 24x24 Gram of [24][4096] fp32 rows, then masked
// contrastive epilogue. Single pass over features (192 MB) -> memory-bound.

#define MROWS 24
#define DIM   4096
#define CH    256            // columns per LDS chunk
#define NCH   (DIM / CH)     // 16 chunks
#define NPAIR 300            // 24*25/2 unique (i<=j) pairs
#define PPW   75             // pairs per wave (4 waves)

typedef float f32x4 __attribute__((ext_vector_type(4)));

constexpr int pair_i(int p) {
    int i = 0;
    while (p >= MROWS - i) { p -= MROWS - i; ++i; }
    return i;
}
constexpr int pair_j(int p) {
    int i = 0;
    while (p >= MROWS - i) { p -= MROWS - i; ++i; }
    return i + p;
}

__device__ __forceinline__ void gll16(const float* g, float* l) {
    // async global->LDS, 16B per lane; LDS dest is wave-uniform base + lane*16
    __builtin_amdgcn_global_load_lds(
        (const __attribute__((address_space(1))) unsigned int*)g,
        (__attribute__((address_space(3))) unsigned int*)l, 16, 0, 0);
}

// Compile-time pair indices (template recursion guarantees constant folding,
// keeping f[] and acc[] in registers).
template<int W, int P>
__device__ __forceinline__ void accum_pairs(const f32x4* f, float* acc) {
    if constexpr (P < PPW) {
        constexpr int gp = W * PPW + P;
        constexpr int i = pair_i(gp);
        constexpr int j = pair_j(gp);
        #pragma unroll
        for (int s = 0; s < 4; ++s)
            acc[P] = fmaf(f[i][s], f[j][s], acc[P]);
        accum_pairs<W, P + 1>(f, acc);
    }
}

template<int W>
__device__ __forceinline__ void accum_chunk(const float* tile, int lane, float* acc) {
    f32x4 f[MROWS];
    #pragma unroll
    for (int r = 0; r < MROWS; ++r)
        f[r] = *(const f32x4*)(tile + r * CH + lane * 4);
    accum_pairs<W, 0>(f, acc);
}

__global__ __launch_bounds__(256, 2)
void brc_loss_kernel(const float* __restrict__ F, float* __restrict__ out, float scale) {
    __shared__ float tile[2][MROWS * CH];   // 2 x 24 KiB double buffer
    __shared__ float Gf[MROWS * MROWS];
    __shared__ float inv_n[MROWS];
    __shared__ float rowv[MROWS];

    const int tid  = threadIdx.x;
    const int lane = tid & 63;
    const int wave = tid >> 6;
    const int b    = blockIdx.x;
    const float* base = F + (size_t)b * (MROWS * DIM);

    float acc[PPW];
    #pragma unroll
    for (int p = 0; p < PPW; ++p) acc[p] = 0.0f;

    // prologue: stage chunk 0 into buf 0 (each wave stages 6 rows)
    {
        const float* src = base + lane * 4;
        #pragma unroll
        for (int q = 0; q < 6; ++q) {
            const int r = wave * 6 + q;
            gll16(src + (size_t)r * DIM, &tile[0][r * CH]);
        }
    }
    __syncthreads();   // drains vmcnt before barrier

    int cur = 0;
    for (int k = 0; k < NCH; ++k) {
        if (k + 1 < NCH) {
            const float* src = base + (k + 1) * CH + lane * 4;
            #pragma unroll
            for (int q = 0; q < 6; ++q) {
                const int r = wave * 6 + q;
                gll16(src + (size_t)r * DIM, &tile[cur ^ 1][r * CH]);
            }
        }
        // compute current chunk while next chunk's loads are in flight
        switch (wave) {
            case 0:  accum_chunk<0>(tile[cur], lane, acc); break;
            case 1:  accum_chunk<1>(tile[cur], lane, acc); break;
            case 2:  accum_chunk<2>(tile[cur], lane, acc); break;
            default: accum_chunk<3>(tile[cur], lane, acc); break;
        }
        __syncthreads();
        cur ^= 1;
    }

    // cross-lane reduction of the 75 per-wave pair accumulators
    #pragma unroll
    for (int p = 0; p < PPW; ++p) {
        float v = acc[p];
        #pragma unroll
        for (int off = 32; off; off >>= 1)
            v += __shfl_xor(v, off, 64);
        if (lane == 0) {
            // decode global pair index -> (i,j) at runtime (lane 0 only)
            int gp = wave * PPW + p;
            int i = 0, rem = gp;
            while (rem >= MROWS - i) { rem -= MROWS - i; ++i; }
            int j = i + rem;
            Gf[i * MROWS + j] = v;
            Gf[j * MROWS + i] = v;
        }
    }
    __syncthreads();

    // epilogue: norms from diagonal, then masked log-softmax rows
    if (tid < MROWS)
        inv_n[tid] = 1.0f / fmaxf(sqrtf(Gf[tid * MROWS + tid]), 1e-12f);
    __syncthreads();

    if (tid < MROWS) {
        const int i = tid;
        const int ci = i % 12;
        const float inv_i = inv_n[i];
        float denom = 0.0f, possum = 0.0f;
        int cnt = 0;
        for (int j = 0; j < MROWS; ++j) {
            if (j == i) continue;
            float l = Gf[i * MROWS + j] * inv_i * inv_n[j] * (1.0f / 0.1f);
            denom += expf(l);                       // is_stable=False: no max-sub
            int cj = j % 12;
            int dc = ci - cj; if (dc < 0) dc = -dc;
            if (dc <= 1) { possum += l; ++cnt; }    // tiled tridiagonal positives
        }
        float mean = (possum - (float)cnt * logf(denom)) / ((float)cnt + 1e-6f);
        rowv[i] = -0.1f * mean;                     // -(T/BASE_T) * mean_log_prob_pos
    }
    __syncthreads();

    if (tid == 0) {
        float s = 0.0f;
        #pragma unroll
        for (int i = 0; i < MROWS; ++i) s += rowv[i];
        atomicAdd(out, s * scale);                  // scale = 1/(24*B)
    }
}

extern "C" void kernel_launch(void* const* d_in, const int* in_sizes, int n_in,
                              void* d_out, int out_size, void* d_ws, size_t ws_size,
                              hipStream_t stream) {
    (void)n_in; (void)d_ws; (void)ws_size; (void)out_size;
    // inputs: [0] outputs (unused), [1] targets (unused), [2] features
    const float* F = (const float*)d_in[2];
    float* out = (float*)d_out;
    const int B = in_sizes[2] / (2 * 12 * DIM);   // 512
    const float scale = 1.0f / (24.0f * (float)B);

    hipMemsetAsync(d_out, 0, sizeof(float), stream);   // out is re-poisoned each call
    brc_loss_kernel<<<dim3(B), dim3(256), 0, stream>>>(F, out, scale);
}